// Round 1
// baseline (4150.683 us; speedup 1.0000x reference)
//
#include <hip/hip_runtime.h>

#define IN_F 1433
#define HID  16
#define OUTC 7

// ---------------------------------------------------------------------------
// K1: XW = x @ W1   (N x 1433) @ (1433 x 16) -> (N x 16)
// One wave (64 lanes) owns 8 rows; lanes split K (coalesced 256B x reads).
// W1 row (64B) loaded per-lane as 4x float4 (L2-resident, amortized over 8 rows).
// Cross-lane butterfly reduction at the end.
// ---------------------------------------------------------------------------
__global__ __launch_bounds__(256) void gcn_k1_xw(
    const float* __restrict__ x, const float* __restrict__ W1,
    float* __restrict__ XW, int N)
{
    const int wave = threadIdx.x >> 6;
    const int lane = threadIdx.x & 63;
    const long row0 = ((long)blockIdx.x * 4 + wave) * 8;
    if (row0 >= N) return;

    float acc[8][16];
#pragma unroll
    for (int r = 0; r < 8; ++r)
#pragma unroll
        for (int j = 0; j < 16; ++j) acc[r][j] = 0.f;

    for (int k = lane; k < IN_F; k += 64) {
        const float4* wp = (const float4*)(W1 + (size_t)k * HID);
        float4 w0 = wp[0], w1 = wp[1], w2 = wp[2], w3 = wp[3];
#pragma unroll
        for (int r = 0; r < 8; ++r) {
            float xv = (row0 + r < N) ? x[(size_t)(row0 + r) * IN_F + k] : 0.f;
            acc[r][0]  += xv * w0.x;  acc[r][1]  += xv * w0.y;
            acc[r][2]  += xv * w0.z;  acc[r][3]  += xv * w0.w;
            acc[r][4]  += xv * w1.x;  acc[r][5]  += xv * w1.y;
            acc[r][6]  += xv * w1.z;  acc[r][7]  += xv * w1.w;
            acc[r][8]  += xv * w2.x;  acc[r][9]  += xv * w2.y;
            acc[r][10] += xv * w2.z;  acc[r][11] += xv * w2.w;
            acc[r][12] += xv * w3.x;  acc[r][13] += xv * w3.y;
            acc[r][14] += xv * w3.z;  acc[r][15] += xv * w3.w;
        }
    }

    // butterfly reduce each of the 128 accumulators over the 64 lanes
#pragma unroll
    for (int r = 0; r < 8; ++r) {
#pragma unroll
        for (int j = 0; j < 16; ++j) {
            float v = acc[r][j];
            v += __shfl_xor(v, 32);
            v += __shfl_xor(v, 16);
            v += __shfl_xor(v, 8);
            v += __shfl_xor(v, 4);
            v += __shfl_xor(v, 2);
            v += __shfl_xor(v, 1);
            acc[r][j] = v;
        }
    }

    if (lane == 0) {
#pragma unroll
        for (int r = 0; r < 8; ++r) {
            if (row0 + r < N) {
                float4* op = (float4*)(XW + (size_t)(row0 + r) * HID);
                op[0] = make_float4(acc[r][0],  acc[r][1],  acc[r][2],  acc[r][3]);
                op[1] = make_float4(acc[r][4],  acc[r][5],  acc[r][6],  acc[r][7]);
                op[2] = make_float4(acc[r][8],  acc[r][9],  acc[r][10], acc[r][11]);
                op[3] = make_float4(acc[r][12], acc[r][13], acc[r][14], acc[r][15]);
            }
        }
    }
}

// ---------------------------------------------------------------------------
// K2: H[row] += val * XW[col]   (16 cols, edge-parallel atomics)
// ---------------------------------------------------------------------------
__global__ __launch_bounds__(256) void gcn_k2_spmm16(
    const int* __restrict__ arow, const int* __restrict__ acol,
    const float* __restrict__ aval, const float* __restrict__ XW,
    float* __restrict__ H, int E)
{
    int e = blockIdx.x * blockDim.x + threadIdx.x;
    if (e >= E) return;
    const int r = arow[e], c = acol[e];
    const float v = aval[e];
    const float4* src = (const float4*)(XW + (size_t)c * HID);
    float4 a = src[0], b = src[1], cc = src[2], d = src[3];
    float* dst = H + (size_t)r * HID;
    atomicAdd(dst + 0,  v * a.x);  atomicAdd(dst + 1,  v * a.y);
    atomicAdd(dst + 2,  v * a.z);  atomicAdd(dst + 3,  v * a.w);
    atomicAdd(dst + 4,  v * b.x);  atomicAdd(dst + 5,  v * b.y);
    atomicAdd(dst + 6,  v * b.z);  atomicAdd(dst + 7,  v * b.w);
    atomicAdd(dst + 8,  v * cc.x); atomicAdd(dst + 9,  v * cc.y);
    atomicAdd(dst + 10, v * cc.z); atomicAdd(dst + 11, v * cc.w);
    atomicAdd(dst + 12, v * d.x);  atomicAdd(dst + 13, v * d.y);
    atomicAdd(dst + 14, v * d.z);  atomicAdd(dst + 15, v * d.w);
}

// ---------------------------------------------------------------------------
// K3: h2 = relu(H + b1) @ W2   (N x 16) @ (16 x 7) -> (N x 7), thread per row
// ---------------------------------------------------------------------------
__global__ __launch_bounds__(256) void gcn_k3_h2(
    const float* __restrict__ H, const float* __restrict__ b1,
    const float* __restrict__ W2, float* __restrict__ h2, int N)
{
    __shared__ float sW2[HID * OUTC];
    __shared__ float sb1[HID];
    if (threadIdx.x < HID * OUTC) sW2[threadIdx.x] = W2[threadIdx.x];
    if (threadIdx.x < HID)        sb1[threadIdx.x] = b1[threadIdx.x];
    __syncthreads();

    int row = blockIdx.x * blockDim.x + threadIdx.x;
    if (row >= N) return;

    const float4* hp = (const float4*)(H + (size_t)row * HID);
    float4 h0 = hp[0], h1 = hp[1], h2v = hp[2], h3 = hp[3];
    float h[16] = {h0.x, h0.y, h0.z, h0.w, h1.x, h1.y, h1.z, h1.w,
                   h2v.x, h2v.y, h2v.z, h2v.w, h3.x, h3.y, h3.z, h3.w};
#pragma unroll
    for (int i = 0; i < HID; ++i) {
        h[i] += sb1[i];
        h[i] = h[i] > 0.f ? h[i] : 0.f;
    }
#pragma unroll
    for (int j = 0; j < OUTC; ++j) {
        float s = 0.f;
#pragma unroll
        for (int i = 0; i < HID; ++i) s += h[i] * sW2[i * OUTC + j];
        h2[(size_t)row * OUTC + j] = s;
    }
}

// ---------------------------------------------------------------------------
// K4: out[row] += val * h2[col]   (7 cols, edge-parallel atomics)
// ---------------------------------------------------------------------------
__global__ __launch_bounds__(256) void gcn_k4_spmm7(
    const int* __restrict__ arow, const int* __restrict__ acol,
    const float* __restrict__ aval, const float* __restrict__ h2,
    float* __restrict__ out, int E)
{
    int e = blockIdx.x * blockDim.x + threadIdx.x;
    if (e >= E) return;
    const int r = arow[e], c = acol[e];
    const float v = aval[e];
    const float* src = h2 + (size_t)c * OUTC;
    float s0 = src[0], s1 = src[1], s2 = src[2], s3 = src[3],
          s4 = src[4], s5 = src[5], s6 = src[6];
    float* dst = out + (size_t)r * OUTC;
    atomicAdd(dst + 0, v * s0); atomicAdd(dst + 1, v * s1);
    atomicAdd(dst + 2, v * s2); atomicAdd(dst + 3, v * s3);
    atomicAdd(dst + 4, v * s4); atomicAdd(dst + 5, v * s5);
    atomicAdd(dst + 6, v * s6);
}

// ---------------------------------------------------------------------------
// K5: out = log_softmax(out + b2) per row (7 classes), in place
// ---------------------------------------------------------------------------
__global__ __launch_bounds__(256) void gcn_k5_lsm(
    float* __restrict__ out, const float* __restrict__ b2, int N)
{
    int row = blockIdx.x * blockDim.x + threadIdx.x;
    if (row >= N) return;
    float* p = out + (size_t)row * OUTC;
    float v[OUTC];
#pragma unroll
    for (int j = 0; j < OUTC; ++j) v[j] = p[j] + b2[j];
    float m = v[0];
#pragma unroll
    for (int j = 1; j < OUTC; ++j) m = fmaxf(m, v[j]);
    float s = 0.f;
#pragma unroll
    for (int j = 0; j < OUTC; ++j) s += expf(v[j] - m);
    const float ls = logf(s);
#pragma unroll
    for (int j = 0; j < OUTC; ++j) p[j] = v[j] - m - ls;
}

// ---------------------------------------------------------------------------
extern "C" void kernel_launch(void* const* d_in, const int* in_sizes, int n_in,
                              void* d_out, int out_size, void* d_ws, size_t ws_size,
                              hipStream_t stream)
{
    const float* x    = (const float*)d_in[0];
    const int*   arow = (const int*)d_in[1];
    const int*   acol = (const int*)d_in[2];
    const float* aval = (const float*)d_in[3];
    const float* W1   = (const float*)d_in[4];
    const float* b1   = (const float*)d_in[5];
    const float* W2   = (const float*)d_in[6];
    const float* b2   = (const float*)d_in[7];
    float* out = (float*)d_out;

    const int N = in_sizes[0] / IN_F;
    const int E = in_sizes[1];

    // workspace layout: [XW : N*16] [H : N*16]; h2 reuses XW (dead after K2)
    float* XW = (float*)d_ws;
    float* H  = XW + (size_t)N * HID;
    float* h2 = XW;

    hipMemsetAsync(H, 0, (size_t)N * HID * sizeof(float), stream);
    hipMemsetAsync(out, 0, (size_t)N * OUTC * sizeof(float), stream);

    // K1: one wave per 8 rows, 4 waves per block -> 32 rows/block
    gcn_k1_xw<<<(N + 31) / 32, 256, 0, stream>>>(x, W1, XW, N);
    // K2: edge-parallel SpMM into H (16 cols)
    gcn_k2_spmm16<<<(E + 255) / 256, 256, 0, stream>>>(arow, acol, aval, XW, H, E);
    // K3: h2 = relu(H + b1) @ W2
    gcn_k3_h2<<<(N + 255) / 256, 256, 0, stream>>>(H, b1, W2, h2, N);
    // K4: edge-parallel SpMM into out (7 cols)
    gcn_k4_spmm7<<<(E + 255) / 256, 256, 0, stream>>>(arow, acol, aval, h2, out, E);
    // K5: log_softmax in place
    gcn_k5_lsm<<<(N + 255) / 256, 256, 0, stream>>>(out, b2, N);
}

// Round 2
// 1046.199 us; speedup vs baseline: 3.9674x; 3.9674x over previous
//
#include <hip/hip_runtime.h>
#include <math.h>

#define IN_F 1433
#define HID  16
#define OUTC 7
#define SCAN_T 1024

// ---------------------------------------------------------------------------
// K1: XW = x @ W1   (N x 1433) @ (1433 x 16) -> (N x 16)
// One wave owns 8 rows; lanes split K (coalesced 256B x reads); butterfly
// reduce. W1 rows amortized over 8 rows/wave.
// ---------------------------------------------------------------------------
__global__ __launch_bounds__(256) void gcn_k1_xw(
    const float* __restrict__ x, const float* __restrict__ W1,
    float* __restrict__ XW, int N)
{
    const int wave = threadIdx.x >> 6;
    const int lane = threadIdx.x & 63;
    const long row0 = ((long)blockIdx.x * 4 + wave) * 8;
    if (row0 >= N) return;

    float acc[8][16];
#pragma unroll
    for (int r = 0; r < 8; ++r)
#pragma unroll
        for (int j = 0; j < 16; ++j) acc[r][j] = 0.f;

    for (int k = lane; k < IN_F; k += 64) {
        const float4* wp = (const float4*)(W1 + (size_t)k * HID);
        float4 w0 = wp[0], w1 = wp[1], w2 = wp[2], w3 = wp[3];
#pragma unroll
        for (int r = 0; r < 8; ++r) {
            float xv = (row0 + r < N) ? x[(size_t)(row0 + r) * IN_F + k] : 0.f;
            acc[r][0]  += xv * w0.x;  acc[r][1]  += xv * w0.y;
            acc[r][2]  += xv * w0.z;  acc[r][3]  += xv * w0.w;
            acc[r][4]  += xv * w1.x;  acc[r][5]  += xv * w1.y;
            acc[r][6]  += xv * w1.z;  acc[r][7]  += xv * w1.w;
            acc[r][8]  += xv * w2.x;  acc[r][9]  += xv * w2.y;
            acc[r][10] += xv * w2.z;  acc[r][11] += xv * w2.w;
            acc[r][12] += xv * w3.x;  acc[r][13] += xv * w3.y;
            acc[r][14] += xv * w3.z;  acc[r][15] += xv * w3.w;
        }
    }

#pragma unroll
    for (int r = 0; r < 8; ++r) {
#pragma unroll
        for (int j = 0; j < 16; ++j) {
            float v = acc[r][j];
            v += __shfl_xor(v, 32);
            v += __shfl_xor(v, 16);
            v += __shfl_xor(v, 8);
            v += __shfl_xor(v, 4);
            v += __shfl_xor(v, 2);
            v += __shfl_xor(v, 1);
            acc[r][j] = v;
        }
    }

    if (lane == 0) {
#pragma unroll
        for (int r = 0; r < 8; ++r) {
            if (row0 + r < N) {
                float4* op = (float4*)(XW + (size_t)(row0 + r) * HID);
                op[0] = make_float4(acc[r][0],  acc[r][1],  acc[r][2],  acc[r][3]);
                op[1] = make_float4(acc[r][4],  acc[r][5],  acc[r][6],  acc[r][7]);
                op[2] = make_float4(acc[r][8],  acc[r][9],  acc[r][10], acc[r][11]);
                op[3] = make_float4(acc[r][12], acc[r][13], acc[r][14], acc[r][15]);
            }
        }
    }
}

// ---------------------------------------------------------------------------
// CSR build: histogram -> single-block scan -> scatter
// ---------------------------------------------------------------------------
__global__ __launch_bounds__(256) void csr_hist(
    const int* __restrict__ arow, int* __restrict__ cnt, int E)
{
    int e = blockIdx.x * blockDim.x + threadIdx.x;
    if (e < E) atomicAdd(&cnt[arow[e]], 1);
}

__global__ __launch_bounds__(SCAN_T) void csr_scan(
    const int* __restrict__ cnt, int* __restrict__ rowptr,
    int* __restrict__ cursor, int N)
{
    __shared__ int sums[SCAN_T];
    const int t = threadIdx.x;
    const int chunk = (N + SCAN_T - 1) / SCAN_T;
    const int lo = t * chunk;
    const int hi = min(lo + chunk, N);
    int s = 0;
    for (int i = lo; i < hi; ++i) s += cnt[i];
    sums[t] = s;
    __syncthreads();
    for (int d = 1; d < SCAN_T; d <<= 1) {
        int a = sums[t];
        int b = (t >= d) ? sums[t - d] : 0;
        __syncthreads();
        sums[t] = a + b;
        __syncthreads();
    }
    int run = sums[t] - s;  // exclusive prefix of this chunk
    for (int i = lo; i < hi; ++i) {
        rowptr[i] = run;
        cursor[i] = run;
        run += cnt[i];
    }
    if (t == SCAN_T - 1) rowptr[N] = sums[SCAN_T - 1];
}

__global__ __launch_bounds__(256) void csr_scatter(
    const int* __restrict__ arow, const int* __restrict__ acol,
    const float* __restrict__ aval, int* __restrict__ cursor,
    int* __restrict__ scol, float* __restrict__ sval, int E)
{
    int e = blockIdx.x * blockDim.x + threadIdx.x;
    if (e >= E) return;
    const int r = arow[e];
    const int pos = atomicAdd(&cursor[r], 1);
    scol[pos] = acol[e];
    sval[pos] = aval[e];
}

// ---------------------------------------------------------------------------
// SpMM 16-col, CSR, no atomics: 16 lanes per row, lane = output column.
// ---------------------------------------------------------------------------
__global__ __launch_bounds__(256) void spmm16_csr(
    const int* __restrict__ rowptr, const int* __restrict__ scol,
    const float* __restrict__ sval, const float* __restrict__ XW,
    float* __restrict__ H, int N)
{
    const int gid = blockIdx.x * blockDim.x + threadIdx.x;
    const int r = gid >> 4;
    const int j = gid & 15;
    if (r >= N) return;
    const int s = rowptr[r], e = rowptr[r + 1];
    float acc = 0.f;
    int k = s;
    for (; k + 4 <= e; k += 4) {
        int   c0 = scol[k],  c1 = scol[k+1], c2 = scol[k+2], c3 = scol[k+3];
        float v0 = sval[k],  v1 = sval[k+1], v2 = sval[k+2], v3 = sval[k+3];
        acc += v0 * XW[(size_t)c0 * HID + j];
        acc += v1 * XW[(size_t)c1 * HID + j];
        acc += v2 * XW[(size_t)c2 * HID + j];
        acc += v3 * XW[(size_t)c3 * HID + j];
    }
    for (; k < e; ++k) acc += sval[k] * XW[(size_t)scol[k] * HID + j];
    H[(size_t)r * HID + j] = acc;
}

// ---------------------------------------------------------------------------
// K3: h2 = relu(H + b1) @ W2, h2 padded to stride 8 (col 7 = 0)
// ---------------------------------------------------------------------------
__global__ __launch_bounds__(256) void gcn_k3_h2(
    const float* __restrict__ H, const float* __restrict__ b1,
    const float* __restrict__ W2, float* __restrict__ h2, int N)
{
    __shared__ float sW2[HID * OUTC];
    __shared__ float sb1[HID];
    if (threadIdx.x < HID * OUTC) sW2[threadIdx.x] = W2[threadIdx.x];
    if (threadIdx.x < HID)        sb1[threadIdx.x] = b1[threadIdx.x];
    __syncthreads();

    int row = blockIdx.x * blockDim.x + threadIdx.x;
    if (row >= N) return;

    const float4* hp = (const float4*)(H + (size_t)row * HID);
    float4 h0 = hp[0], h1 = hp[1], h2v = hp[2], h3 = hp[3];
    float h[16] = {h0.x, h0.y, h0.z, h0.w, h1.x, h1.y, h1.z, h1.w,
                   h2v.x, h2v.y, h2v.z, h2v.w, h3.x, h3.y, h3.z, h3.w};
#pragma unroll
    for (int i = 0; i < HID; ++i) {
        h[i] += sb1[i];
        h[i] = h[i] > 0.f ? h[i] : 0.f;
    }
    float o[8];
#pragma unroll
    for (int j = 0; j < OUTC; ++j) {
        float s = 0.f;
#pragma unroll
        for (int i = 0; i < HID; ++i) s += h[i] * sW2[i * OUTC + j];
        o[j] = s;
    }
    o[7] = 0.f;
    float4* op = (float4*)(h2 + (size_t)row * 8);
    op[0] = make_float4(o[0], o[1], o[2], o[3]);
    op[1] = make_float4(o[4], o[5], o[6], o[7]);
}

// ---------------------------------------------------------------------------
// SpMM 7-col (stride-8 h2) + fused log_softmax: 8 lanes per row.
// ---------------------------------------------------------------------------
__global__ __launch_bounds__(256) void spmm7_lsm(
    const int* __restrict__ rowptr, const int* __restrict__ scol,
    const float* __restrict__ sval, const float* __restrict__ h2,
    const float* __restrict__ b2, float* __restrict__ out, int N)
{
    const int gid = blockIdx.x * blockDim.x + threadIdx.x;
    const int r = gid >> 3;
    const int j = gid & 7;
    if (r >= N) return;
    const int s = rowptr[r], e = rowptr[r + 1];
    float acc = 0.f;
    int k = s;
    for (; k + 4 <= e; k += 4) {
        int   c0 = scol[k],  c1 = scol[k+1], c2 = scol[k+2], c3 = scol[k+3];
        float v0 = sval[k],  v1 = sval[k+1], v2 = sval[k+2], v3 = sval[k+3];
        acc += v0 * h2[(size_t)c0 * 8 + j];
        acc += v1 * h2[(size_t)c1 * 8 + j];
        acc += v2 * h2[(size_t)c2 * 8 + j];
        acc += v3 * h2[(size_t)c3 * 8 + j];
    }
    for (; k < e; ++k) acc += sval[k] * h2[(size_t)scol[k] * 8 + j];

    float val = acc + ((j < OUTC) ? b2[j] : 0.f);
    float m = (j < OUTC) ? val : -INFINITY;
    m = fmaxf(m, __shfl_xor(m, 1));
    m = fmaxf(m, __shfl_xor(m, 2));
    m = fmaxf(m, __shfl_xor(m, 4));
    float ex = (j < OUTC) ? expf(val - m) : 0.f;
    ex += __shfl_xor(ex, 1);
    ex += __shfl_xor(ex, 2);
    ex += __shfl_xor(ex, 4);
    if (j < OUTC) out[(size_t)r * OUTC + j] = val - m - logf(ex);
}

// ---------------------------------------------------------------------------
// Fallback path kernels (atomic-based, used only if ws too small)
// ---------------------------------------------------------------------------
__global__ __launch_bounds__(256) void gcn_k2_spmm16_atomic(
    const int* __restrict__ arow, const int* __restrict__ acol,
    const float* __restrict__ aval, const float* __restrict__ XW,
    float* __restrict__ H, int E)
{
    int e = blockIdx.x * blockDim.x + threadIdx.x;
    if (e >= E) return;
    const int r = arow[e], c = acol[e];
    const float v = aval[e];
    const float4* src = (const float4*)(XW + (size_t)c * HID);
    float4 a = src[0], b = src[1], cc = src[2], d = src[3];
    float* dst = H + (size_t)r * HID;
    atomicAdd(dst + 0,  v * a.x);  atomicAdd(dst + 1,  v * a.y);
    atomicAdd(dst + 2,  v * a.z);  atomicAdd(dst + 3,  v * a.w);
    atomicAdd(dst + 4,  v * b.x);  atomicAdd(dst + 5,  v * b.y);
    atomicAdd(dst + 6,  v * b.z);  atomicAdd(dst + 7,  v * b.w);
    atomicAdd(dst + 8,  v * cc.x); atomicAdd(dst + 9,  v * cc.y);
    atomicAdd(dst + 10, v * cc.z); atomicAdd(dst + 11, v * cc.w);
    atomicAdd(dst + 12, v * d.x);  atomicAdd(dst + 13, v * d.y);
    atomicAdd(dst + 14, v * d.z);  atomicAdd(dst + 15, v * d.w);
}

__global__ __launch_bounds__(256) void gcn_k4_spmm7_atomic(
    const int* __restrict__ arow, const int* __restrict__ acol,
    const float* __restrict__ aval, const float* __restrict__ h2,
    float* __restrict__ out, int E)
{
    int e = blockIdx.x * blockDim.x + threadIdx.x;
    if (e >= E) return;
    const int r = arow[e], c = acol[e];
    const float v = aval[e];
    const float* src = h2 + (size_t)c * 8;
    float* dst = out + (size_t)r * OUTC;
#pragma unroll
    for (int j = 0; j < OUTC; ++j) atomicAdd(dst + j, v * src[j]);
}

__global__ __launch_bounds__(256) void gcn_k5_lsm(
    float* __restrict__ out, const float* __restrict__ b2, int N)
{
    int row = blockIdx.x * blockDim.x + threadIdx.x;
    if (row >= N) return;
    float* p = out + (size_t)row * OUTC;
    float v[OUTC];
#pragma unroll
    for (int j = 0; j < OUTC; ++j) v[j] = p[j] + b2[j];
    float m = v[0];
#pragma unroll
    for (int j = 1; j < OUTC; ++j) m = fmaxf(m, v[j]);
    float s = 0.f;
#pragma unroll
    for (int j = 0; j < OUTC; ++j) s += expf(v[j] - m);
    const float ls = logf(s);
#pragma unroll
    for (int j = 0; j < OUTC; ++j) p[j] = v[j] - m - ls;
}

// ---------------------------------------------------------------------------
extern "C" void kernel_launch(void* const* d_in, const int* in_sizes, int n_in,
                              void* d_out, int out_size, void* d_ws, size_t ws_size,
                              hipStream_t stream)
{
    const float* x    = (const float*)d_in[0];
    const int*   arow = (const int*)d_in[1];
    const int*   acol = (const int*)d_in[2];
    const float* aval = (const float*)d_in[3];
    const float* W1   = (const float*)d_in[4];
    const float* b1   = (const float*)d_in[5];
    const float* W2   = (const float*)d_in[6];
    const float* b2   = (const float*)d_in[7];
    float* out = (float*)d_out;

    const int N = in_sizes[0] / IN_F;
    const int E = in_sizes[1];

    // workspace layout (fast path):
    // [scol E] [sval E] [XW N*16] [H N*16] [cnt N] [cursor N] [rowptr N+1]
    char* w = (char*)d_ws;
    int*   scol   = (int*)w;    w += (size_t)E * 4;
    float* sval   = (float*)w;  w += (size_t)E * 4;
    float* XW     = (float*)w;  w += (size_t)N * HID * 4;
    float* H      = (float*)w;  w += (size_t)N * HID * 4;
    int*   cnt    = (int*)w;    w += (size_t)N * 4;
    int*   cursor = (int*)w;    w += (size_t)N * 4;
    int*   rowptr = (int*)w;    w += (size_t)(N + 1) * 4;
    const size_t need = (size_t)(w - (char*)d_ws);
    float* h2 = XW;  // XW dead after spmm16; h2 needs N*8*4 <= N*16*4

    const int eb = (E + 255) / 256;
    const int nb = (N + 255) / 256;

    if (ws_size >= need) {
        // ---- fast path: CSR sort + gather SpMM (no fp atomics) ----
        hipMemsetAsync(cnt, 0, (size_t)N * 4, stream);
        csr_hist<<<eb, 256, 0, stream>>>(arow, cnt, E);
        csr_scan<<<1, SCAN_T, 0, stream>>>(cnt, rowptr, cursor, N);
        csr_scatter<<<eb, 256, 0, stream>>>(arow, acol, aval, cursor, scol, sval, E);

        gcn_k1_xw<<<(N + 31) / 32, 256, 0, stream>>>(x, W1, XW, N);
        spmm16_csr<<<(N * 16 + 255) / 256, 256, 0, stream>>>(rowptr, scol, sval, XW, H, N);
        gcn_k3_h2<<<nb, 256, 0, stream>>>(H, b1, W2, h2, N);
        spmm7_lsm<<<(N * 8 + 255) / 256, 256, 0, stream>>>(rowptr, scol, sval, h2, b2, out, N);
    } else {
        // ---- fallback: round-1 atomic path (needs only XW+H = 12.8 MB) ----
        float* XWf = (float*)d_ws;
        float* Hf  = XWf + (size_t)N * HID;
        float* h2f = XWf;
        hipMemsetAsync(Hf, 0, (size_t)N * HID * sizeof(float), stream);
        hipMemsetAsync(out, 0, (size_t)N * OUTC * sizeof(float), stream);
        gcn_k1_xw<<<(N + 31) / 32, 256, 0, stream>>>(x, W1, XWf, N);
        gcn_k2_spmm16_atomic<<<eb, 256, 0, stream>>>(arow, acol, aval, XWf, Hf, E);
        gcn_k3_h2<<<nb, 256, 0, stream>>>(Hf, b1, W2, h2f, N);
        gcn_k4_spmm7_atomic<<<eb, 256, 0, stream>>>(arow, acol, aval, h2f, out, E);
        gcn_k5_lsm<<<nb, 256, 0, stream>>>(out, b2, N);
    }
}

// Round 3
// 946.619 us; speedup vs baseline: 4.3847x; 1.1052x over previous
//
#include <hip/hip_runtime.h>
#include <math.h>

#define IN_F 1433
#define HID  16
#define OUTC 7
#define SCAN_T 1024

// ---------------------------------------------------------------------------
// K1: XW = x @ W1   (N x 1433) @ (1433 x 16) -> (N x 16)
// Lane decomposition: lane = j4*16 + ks. 16 ks-lanes split K, 4 j4-groups
// each own 4 output columns. acc[4][4] per lane (4 rows/wave) -> ~80 VGPRs,
// 20 independent loads per iteration, 64-shuffle epilogue.
// ---------------------------------------------------------------------------
__global__ __launch_bounds__(256) void gcn_k1_xw(
    const float* __restrict__ x, const float* __restrict__ W1,
    float* __restrict__ XW, int N)
{
    const int wave = threadIdx.x >> 6;
    const int lane = threadIdx.x & 63;
    const int ks   = lane & 15;   // k-slice within wave
    const int j4   = lane >> 4;   // owns output cols j4*4 .. j4*4+3
    const int row0 = (blockIdx.x * 4 + wave) * 4;
    if (row0 >= N) return;

    const float* xr[4];
#pragma unroll
    for (int r = 0; r < 4; ++r) {
        int row = row0 + r; if (row > N - 1) row = N - 1;  // clamp, mask at write
        xr[r] = x + (size_t)row * IN_F;
    }
    const float4* W1v = (const float4*)W1;

    float acc[4][4];
#pragma unroll
    for (int r = 0; r < 4; ++r)
#pragma unroll
        for (int c = 0; c < 4; ++c) acc[r][c] = 0.f;

    // k = it*64 + u*16 + ks ; 23*64 = 1472 >= 1433
#pragma unroll 1
    for (int it = 0; it < 23; ++it) {
        const int kb = it * 64 + ks;
#pragma unroll
        for (int u = 0; u < 4; ++u) {
            const int k  = kb + u * 16;
            const bool ok = (k < IN_F);
            const int kk = ok ? k : (IN_F - 1);
            const float4 w = W1v[kk * 4 + j4];
            float xv[4];
#pragma unroll
            for (int r = 0; r < 4; ++r) xv[r] = ok ? xr[r][k] : 0.f;
#pragma unroll
            for (int r = 0; r < 4; ++r) {
                acc[r][0] += xv[r] * w.x;
                acc[r][1] += xv[r] * w.y;
                acc[r][2] += xv[r] * w.z;
                acc[r][3] += xv[r] * w.w;
            }
        }
    }

    // reduce over the 16 ks-lanes (lane bits 0..3)
#pragma unroll
    for (int m = 1; m <= 8; m <<= 1)
#pragma unroll
        for (int r = 0; r < 4; ++r)
#pragma unroll
            for (int c = 0; c < 4; ++c)
                acc[r][c] += __shfl_xor(acc[r][c], m);

    if (ks < 4) {
        const int row = row0 + ks;
        if (row < N) {
            float4 o;   // static-index selects (no runtime register indexing)
            o.x = (ks==0)?acc[0][0]:(ks==1)?acc[1][0]:(ks==2)?acc[2][0]:acc[3][0];
            o.y = (ks==0)?acc[0][1]:(ks==1)?acc[1][1]:(ks==2)?acc[2][1]:acc[3][1];
            o.z = (ks==0)?acc[0][2]:(ks==1)?acc[1][2]:(ks==2)?acc[2][2]:acc[3][2];
            o.w = (ks==0)?acc[0][3]:(ks==1)?acc[1][3]:(ks==2)?acc[2][3]:acc[3][3];
            *(float4*)(XW + (size_t)row * HID + j4 * 4) = o;
        }
    }
}

// ---------------------------------------------------------------------------
// CSR build: histogram -> single-block scan -> scatter (packed col+val)
// ---------------------------------------------------------------------------
__global__ __launch_bounds__(256) void csr_hist(
    const int* __restrict__ arow, int* __restrict__ cnt, int E)
{
    int e = blockIdx.x * blockDim.x + threadIdx.x;
    if (e < E) atomicAdd(&cnt[arow[e]], 1);
}

__global__ __launch_bounds__(SCAN_T) void csr_scan(
    const int* __restrict__ cnt, int* __restrict__ rowptr,
    int* __restrict__ cursor, int N)
{
    __shared__ int sums[SCAN_T];
    const int t = threadIdx.x;
    const int chunk = (N + SCAN_T - 1) / SCAN_T;
    const int lo = t * chunk;
    const int hi = min(lo + chunk, N);
    int s = 0;
    for (int i = lo; i < hi; ++i) s += cnt[i];
    sums[t] = s;
    __syncthreads();
    for (int d = 1; d < SCAN_T; d <<= 1) {
        int a = sums[t];
        int b = (t >= d) ? sums[t - d] : 0;
        __syncthreads();
        sums[t] = a + b;
        __syncthreads();
    }
    int run = sums[t] - s;  // exclusive prefix of this chunk
    for (int i = lo; i < hi; ++i) {
        rowptr[i] = run;
        cursor[i] = run;
        run += cnt[i];
    }
    if (t == SCAN_T - 1) rowptr[N] = sums[SCAN_T - 1];
}

__global__ __launch_bounds__(256) void csr_scatter(
    const int* __restrict__ arow, const int* __restrict__ acol,
    const float* __restrict__ aval, int* __restrict__ cursor,
    int2* __restrict__ ecv, int E)
{
    int e = blockIdx.x * blockDim.x + threadIdx.x;
    if (e >= E) return;
    const int r = arow[e];
    const int pos = atomicAdd(&cursor[r], 1);
    ecv[pos] = make_int2(acol[e], __float_as_int(aval[e]));
}

// ---------------------------------------------------------------------------
// SpMM(16) + relu(.+b1) @ W2 fused: one wave per row.
// lane = w*16 + j : 16 j-lanes = columns of XW, 4 w-ways split the edges.
// ---------------------------------------------------------------------------
__global__ __launch_bounds__(256) void spmm16_h2(
    const int* __restrict__ rowptr, const int2* __restrict__ ecv,
    const float* __restrict__ XW, const float* __restrict__ b1,
    const float* __restrict__ W2, float* __restrict__ h2, int N)
{
    const int gw = (int)((blockIdx.x * (size_t)blockDim.x + threadIdx.x) >> 6);
    if (gw >= N) return;
    const int lane = threadIdx.x & 63;
    const int j = lane & 15;
    const int w = lane >> 4;
    const int s = rowptr[gw], e = rowptr[gw + 1];

    float acc = 0.f;
    int k = s + w;
    while (k + 4 < e) {
        int2 a = ecv[k], b = ecv[k + 4];
        acc += __int_as_float(a.y) * XW[(size_t)a.x * HID + j];
        acc += __int_as_float(b.y) * XW[(size_t)b.x * HID + j];
        k += 8;
    }
    if (k < e) {
        int2 a = ecv[k];
        acc += __int_as_float(a.y) * XW[(size_t)a.x * HID + j];
    }
    // reduce the 4 edge-ways (lane bits 4,5)
    acc += __shfl_xor(acc, 16);
    acc += __shfl_xor(acc, 32);

    // fused layer-2 projection: h = relu(acc + b1[j]); p = h * W2[j][:]
    const float h = fmaxf(acc + b1[j], 0.f);
    float p[OUTC];
#pragma unroll
    for (int c = 0; c < OUTC; ++c) p[c] = h * W2[j * OUTC + c];
#pragma unroll
    for (int m = 1; m <= 8; m <<= 1)
#pragma unroll
        for (int c = 0; c < OUTC; ++c) p[c] += __shfl_xor(p[c], m);

    if (lane < 8) {
        float o = p[0];
        o = (lane == 1) ? p[1] : o;
        o = (lane == 2) ? p[2] : o;
        o = (lane == 3) ? p[3] : o;
        o = (lane == 4) ? p[4] : o;
        o = (lane == 5) ? p[5] : o;
        o = (lane == 6) ? p[6] : o;
        if (lane == 7) o = 0.f;           // pad col
        h2[(size_t)gw * 8 + lane] = o;
    }
}

// ---------------------------------------------------------------------------
// SpMM(7, stride-8 h2) + fused log_softmax: one wave per row.
// lane = w*8 + j : 8 j-lanes = classes (+pad), 8 w-ways split the edges.
// ---------------------------------------------------------------------------
__global__ __launch_bounds__(256) void spmm7_lsm(
    const int* __restrict__ rowptr, const int2* __restrict__ ecv,
    const float* __restrict__ h2, const float* __restrict__ b2,
    float* __restrict__ out, int N)
{
    const int gw = (int)((blockIdx.x * (size_t)blockDim.x + threadIdx.x) >> 6);
    if (gw >= N) return;
    const int lane = threadIdx.x & 63;
    const int j = lane & 7;
    const int w = lane >> 3;
    const int s = rowptr[gw], e = rowptr[gw + 1];

    float acc = 0.f;
    int k = s + w;
    while (k + 8 < e) {
        int2 a = ecv[k], b = ecv[k + 8];
        acc += __int_as_float(a.y) * h2[(size_t)a.x * 8 + j];
        acc += __int_as_float(b.y) * h2[(size_t)b.x * 8 + j];
        k += 16;
    }
    if (k < e) {
        int2 a = ecv[k];
        acc += __int_as_float(a.y) * h2[(size_t)a.x * 8 + j];
    }
    // reduce the 8 edge-ways (lane bits 3,4,5)
    acc += __shfl_xor(acc, 8);
    acc += __shfl_xor(acc, 16);
    acc += __shfl_xor(acc, 32);

    const float bias = b2[(j < OUTC) ? j : 0];
    const float val  = acc + bias;                 // j==7 masked below
    float mx = (j < OUTC) ? val : -INFINITY;
    mx = fmaxf(mx, __shfl_xor(mx, 1));
    mx = fmaxf(mx, __shfl_xor(mx, 2));
    mx = fmaxf(mx, __shfl_xor(mx, 4));
    float ex = (j < OUTC) ? expf(val - mx) : 0.f;
    ex += __shfl_xor(ex, 1);
    ex += __shfl_xor(ex, 2);
    ex += __shfl_xor(ex, 4);
    if (lane < OUTC) out[(size_t)gw * OUTC + lane] = val - mx - logf(ex);
}

// ---------------------------------------------------------------------------
// Fallback path kernels (atomic-based, used only if ws too small)
// ---------------------------------------------------------------------------
__global__ __launch_bounds__(256) void gcn_k2_spmm16_atomic(
    const int* __restrict__ arow, const int* __restrict__ acol,
    const float* __restrict__ aval, const float* __restrict__ XW,
    float* __restrict__ H, int E)
{
    int e = blockIdx.x * blockDim.x + threadIdx.x;
    if (e >= E) return;
    const int r = arow[e], c = acol[e];
    const float v = aval[e];
    const float4* src = (const float4*)(XW + (size_t)c * HID);
    float4 a = src[0], b = src[1], cc = src[2], d = src[3];
    float* dst = H + (size_t)r * HID;
    atomicAdd(dst + 0,  v * a.x);  atomicAdd(dst + 1,  v * a.y);
    atomicAdd(dst + 2,  v * a.z);  atomicAdd(dst + 3,  v * a.w);
    atomicAdd(dst + 4,  v * b.x);  atomicAdd(dst + 5,  v * b.y);
    atomicAdd(dst + 6,  v * b.z);  atomicAdd(dst + 7,  v * b.w);
    atomicAdd(dst + 8,  v * cc.x); atomicAdd(dst + 9,  v * cc.y);
    atomicAdd(dst + 10, v * cc.z); atomicAdd(dst + 11, v * cc.w);
    atomicAdd(dst + 12, v * d.x);  atomicAdd(dst + 13, v * d.y);
    atomicAdd(dst + 14, v * d.z);  atomicAdd(dst + 15, v * d.w);
}

__global__ __launch_bounds__(256) void gcn_k3_h2(
    const float* __restrict__ H, const float* __restrict__ b1,
    const float* __restrict__ W2, float* __restrict__ h2, int N)
{
    __shared__ float sW2[HID * OUTC];
    __shared__ float sb1[HID];
    if (threadIdx.x < HID * OUTC) sW2[threadIdx.x] = W2[threadIdx.x];
    if (threadIdx.x < HID)        sb1[threadIdx.x] = b1[threadIdx.x];
    __syncthreads();

    int row = blockIdx.x * blockDim.x + threadIdx.x;
    if (row >= N) return;

    const float4* hp = (const float4*)(H + (size_t)row * HID);
    float4 h0 = hp[0], h1 = hp[1], h2v = hp[2], h3 = hp[3];
    float h[16] = {h0.x, h0.y, h0.z, h0.w, h1.x, h1.y, h1.z, h1.w,
                   h2v.x, h2v.y, h2v.z, h2v.w, h3.x, h3.y, h3.z, h3.w};
#pragma unroll
    for (int i = 0; i < HID; ++i) {
        h[i] += sb1[i];
        h[i] = h[i] > 0.f ? h[i] : 0.f;
    }
    float o[8];
#pragma unroll
    for (int jj = 0; jj < OUTC; ++jj) {
        float sum = 0.f;
#pragma unroll
        for (int i = 0; i < HID; ++i) sum += h[i] * sW2[i * OUTC + jj];
        o[jj] = sum;
    }
    o[7] = 0.f;
    float4* op = (float4*)(h2 + (size_t)row * 8);
    op[0] = make_float4(o[0], o[1], o[2], o[3]);
    op[1] = make_float4(o[4], o[5], o[6], o[7]);
}

__global__ __launch_bounds__(256) void gcn_k4_spmm7_atomic(
    const int* __restrict__ arow, const int* __restrict__ acol,
    const float* __restrict__ aval, const float* __restrict__ h2,
    float* __restrict__ out, int E)
{
    int e = blockIdx.x * blockDim.x + threadIdx.x;
    if (e >= E) return;
    const int r = arow[e], c = acol[e];
    const float v = aval[e];
    const float* src = h2 + (size_t)c * 8;
    float* dst = out + (size_t)r * OUTC;
#pragma unroll
    for (int jj = 0; jj < OUTC; ++jj) atomicAdd(dst + jj, v * src[jj]);
}

__global__ __launch_bounds__(256) void gcn_k5_lsm(
    float* __restrict__ out, const float* __restrict__ b2, int N)
{
    int row = blockIdx.x * blockDim.x + threadIdx.x;
    if (row >= N) return;
    float* p = out + (size_t)row * OUTC;
    float v[OUTC];
#pragma unroll
    for (int jj = 0; jj < OUTC; ++jj) v[jj] = p[jj] + b2[jj];
    float m = v[0];
#pragma unroll
    for (int jj = 1; jj < OUTC; ++jj) m = fmaxf(m, v[jj]);
    float s = 0.f;
#pragma unroll
    for (int jj = 0; jj < OUTC; ++jj) s += expf(v[jj] - m);
    const float ls = logf(s);
#pragma unroll
    for (int jj = 0; jj < OUTC; ++jj) p[jj] = v[jj] - m - ls;
}

// ---------------------------------------------------------------------------
extern "C" void kernel_launch(void* const* d_in, const int* in_sizes, int n_in,
                              void* d_out, int out_size, void* d_ws, size_t ws_size,
                              hipStream_t stream)
{
    const float* x    = (const float*)d_in[0];
    const int*   arow = (const int*)d_in[1];
    const int*   acol = (const int*)d_in[2];
    const float* aval = (const float*)d_in[3];
    const float* W1   = (const float*)d_in[4];
    const float* b1   = (const float*)d_in[5];
    const float* W2   = (const float*)d_in[6];
    const float* b2   = (const float*)d_in[7];
    float* out = (float*)d_out;

    const int N = in_sizes[0] / IN_F;
    const int E = in_sizes[1];

    // fast-path ws layout: [ecv E*8] [XW N*16f] [h2 N*8f] [cnt N] [cursor N] [rowptr N+1]
    char* wsp = (char*)d_ws;
    int2*  ecv    = (int2*)wsp;   wsp += (size_t)E * 8;
    float* XW     = (float*)wsp;  wsp += (size_t)N * HID * 4;
    float* h2     = (float*)wsp;  wsp += (size_t)N * 8 * 4;
    int*   cnt    = (int*)wsp;    wsp += (size_t)N * 4;
    int*   cursor = (int*)wsp;    wsp += (size_t)N * 4;
    int*   rowptr = (int*)wsp;    wsp += (size_t)(N + 1) * 4;
    const size_t need = (size_t)(wsp - (char*)d_ws);

    const int eb = (E + 255) / 256;
    const int nb = (N + 255) / 256;

    if (ws_size >= need) {
        // ---- fast path: CSR + gather SpMM, no fp atomics, K3 fused ----
        hipMemsetAsync(cnt, 0, (size_t)N * 4, stream);
        csr_hist<<<eb, 256, 0, stream>>>(arow, cnt, E);
        csr_scan<<<1, SCAN_T, 0, stream>>>(cnt, rowptr, cursor, N);
        csr_scatter<<<eb, 256, 0, stream>>>(arow, acol, aval, cursor, ecv, E);

        gcn_k1_xw<<<(N + 15) / 16, 256, 0, stream>>>(x, W1, XW, N);
        spmm16_h2<<<(N + 3) / 4, 256, 0, stream>>>(rowptr, ecv, XW, b1, W2, h2, N);
        spmm7_lsm<<<(N + 3) / 4, 256, 0, stream>>>(rowptr, ecv, h2, b2, out, N);
    } else {
        // ---- fallback: atomic path (needs only XW+H = 12.8 MB) ----
        float* XWf = (float*)d_ws;
        float* Hf  = XWf + (size_t)N * HID;
        float* h2f = XWf;   // XW dead after spmm16_atomic
        hipMemsetAsync(Hf, 0, (size_t)N * HID * sizeof(float), stream);
        hipMemsetAsync(out, 0, (size_t)N * OUTC * sizeof(float), stream);
        gcn_k1_xw<<<(N + 15) / 16, 256, 0, stream>>>(x, W1, XWf, N);
        gcn_k2_spmm16_atomic<<<eb, 256, 0, stream>>>(arow, acol, aval, XWf, Hf, E);
        gcn_k3_h2<<<nb, 256, 0, stream>>>(Hf, b1, W2, h2f, N);
        gcn_k4_spmm7_atomic<<<eb, 256, 0, stream>>>(arow, acol, aval, h2f, out, E);
        gcn_k5_lsm<<<nb, 256, 0, stream>>>(out, b2, N);
    }
}